// Round 9
// baseline (366.157 us; speedup 1.0000x reference)
//
#include <hip/hip_runtime.h>

// ---------------------------------------------------------------------------
// 12-qubit state-vector sim, one sample per 64-lane wave, 2 samples/block.
// Storage index p (12 bits): bits 0..5 = per-thread local index j,
// bits 6..11 = lane id. Logical index k = M*p over GF(2); CNOTs folded into
// M at compile time; each Rot gate = pair-mask (column of M^-1) + side-mask
// (row of M). Wire w <-> bit (11-w) of k (PennyLane big-endian).
// Invariant: parity(pair & side) == 1 (12-bit); partner's local side bit is
// sj ^ parity(pml & sml).
//
// Pipe assignment (R7, kept): per-gate compile-time choice
//   DPP cost <= 2 -> VALU path (quad_perm / mirrors / permlane16/32_swap)
//   DPP cost  > 2 -> DS path (ds_bpermute via __shfl_xor, batched 16)
//
// Round-9 changes:
//  - blocks 256 -> 128 threads (2 waves), __launch_bounds__(128,3):
//    R8 showed a 256-thr block (8 waves) is the only resident block at
//    2 waves/SIMD; 128-thr blocks + 170-reg cap let 3 blocks (12 waves)
//    co-reside -> 3 waves/SIMD to cover the ~25% DS-stall idle.
//    WRITE_SIZE is the spill canary (R3: scratch spill = 230 MB writes).
//  - measurement: 6-stage local Walsh-Hadamard butterfly (384 adds) replaces
//    the 12-mask sign loop (768 adds); the 12 <Z_q> sums become lookups
//    w[meas[q]&63].
// ---------------------------------------------------------------------------

#define N_GATES 48

typedef float v2f __attribute__((ext_vector_type(2)));

#if __has_builtin(__builtin_amdgcn_permlane16_swap) && __has_builtin(__builtin_amdgcn_permlane32_swap)
#define HAS_PLSWAP 1
#else
#define HAS_PLSWAP 0
#endif

struct Circ {
    unsigned pair[N_GATES];
    unsigned side[N_GATES];
    unsigned meas[12];
};

constexpr Circ make_circ() {
    Circ c{};
    unsigned Mrow[12] = {}, Ucol[12] = {};   // M rows, M^-1 columns
    for (int i = 0; i < 12; ++i) { Mrow[i] = 1u << i; Ucol[i] = 1u << i; }
    int g = 0;
    for (int l = 0; l < 4; ++l) {
        for (int w = 0; w < 12; ++w) {
            int b = 11 - w;
            c.pair[g] = Ucol[b];
            c.side[g] = Mrow[b];
            ++g;
        }
        // CNOT chain: (0,1),(1,2),...,(10,11) then (11,0); bits c=11-i, t=10-i
        for (int i = 0; i < 11; ++i) {
            int cb = 11 - i, tb = 10 - i;
            Mrow[tb] ^= Mrow[cb];
            Ucol[cb] ^= Ucol[tb];
        }
        Mrow[11] ^= Mrow[0];   // CNOT(11 -> 0): control bit 0, target bit 11
        Ucol[0]  ^= Ucol[11];
    }
    for (int w = 0; w < 12; ++w) c.meas[w] = Mrow[11 - w];
    return c;
}

constexpr Circ CIRC = make_circ();

// c-th pair slot for in-thread/mixed gates: insert a 0 bit at position MSB
__device__ __forceinline__ constexpr int pidx(int c, int msb) {
    return ((c & ~(msb - 1)) << 1) | (c & (msb - 1));
}

// DPP atom cost of a lane-xor mask
constexpr int dpp_cost(unsigned pmh) {
    constexpr int low[16] = {0,1,1,1,2,2,2,1,2,3,3,3,2,2,2,1};
    int c = low[pmh & 15u];
    if (pmh & 16u) c += 2;
    if (pmh & 32u) c += 2;
    return c;
}

// ---- VALU-pipe lane-xor primitives --------------------------------------
__device__ __forceinline__ int dpp1(int w){ return __builtin_amdgcn_mov_dpp(w, 0xB1,  0xF, 0xF, true); }
__device__ __forceinline__ int dpp2(int w){ return __builtin_amdgcn_mov_dpp(w, 0x4E,  0xF, 0xF, true); }
__device__ __forceinline__ int dpp3(int w){ return __builtin_amdgcn_mov_dpp(w, 0x1B,  0xF, 0xF, true); }
__device__ __forceinline__ int dpp7(int w){ return __builtin_amdgcn_mov_dpp(w, 0x141, 0xF, 0xF, true); }
__device__ __forceinline__ int dppF(int w){ return __builtin_amdgcn_mov_dpp(w, 0x140, 0xF, 0xF, true); }

template <unsigned V>
__device__ __forceinline__ int dpp_low(int w) {
    if constexpr (V == 0)  return w;
    else if constexpr (V == 1)  return dpp1(w);
    else if constexpr (V == 2)  return dpp2(w);
    else if constexpr (V == 3)  return dpp3(w);
    else if constexpr (V == 4)  return dpp3(dpp7(w));
    else if constexpr (V == 5)  return dpp2(dpp7(w));
    else if constexpr (V == 6)  return dpp1(dpp7(w));
    else if constexpr (V == 7)  return dpp7(w);
    else if constexpr (V == 8)  return dpp7(dppF(w));
    else if constexpr (V == 9)  return dpp1(dpp7(dppF(w)));
    else if constexpr (V == 10) return dpp2(dpp7(dppF(w)));
    else if constexpr (V == 11) return dpp3(dpp7(dppF(w)));
    else if constexpr (V == 12) return dpp3(dppF(w));
    else if constexpr (V == 13) return dpp2(dppF(w));
    else if constexpr (V == 14) return dpp1(dppF(w));
    else return dppF(w);   // V == 15
}

template <unsigned PMH>
__device__ __forceinline__ unsigned xword(unsigned w, bool l16, bool l32) {
    unsigned t = (unsigned)dpp_low<PMH & 15u>((int)w);
#if HAS_PLSWAP
    if constexpr ((PMH & 16u) != 0) {
        auto r = __builtin_amdgcn_permlane16_swap(t, t, false, false);
        t = l16 ? r[0] : r[1];
    }
    if constexpr ((PMH & 32u) != 0) {
        auto r = __builtin_amdgcn_permlane32_swap(t, t, false, false);
        t = l32 ? r[0] : r[1];
    }
#else
    if constexpr ((PMH & 48u) != 0)
        t = (unsigned)__shfl_xor((int)t, (int)(PMH & 48u), 64);
#endif
    return t;
}

template <unsigned PMH>
__device__ __forceinline__ v2f xpartner(v2f v, bool l16, bool l32) {
    union { v2f f; unsigned u[2]; } a;
    a.f = v;
    a.u[0] = xword<PMH>(a.u[0], l16, l32);
    a.u[1] = xword<PMH>(a.u[1], l16, l32);
    return a.f;
}

// acc + coef * X (complex), packed: coefR = {cr,cr}, coefN = {-ci,ci}
__device__ __forceinline__ v2f cmadd(v2f coefR, v2f coefN, v2f X, v2f acc) {
    acc = __builtin_elementwise_fma(coefR, X, acc);
    acc = __builtin_elementwise_fma(coefN, X.yx, acc);
    return acc;
}
__device__ __forceinline__ v2f cmul(v2f coefR, v2f coefN, v2f X) {
    return __builtin_elementwise_fma(coefR, X, coefN * X.yx);
}

template <int G>
__device__ __forceinline__ void apply_gate(v2f (&st)[64], const float* __restrict__ m,
                                           int lane, bool l16, bool l32) {
    constexpr unsigned pm  = CIRC.pair[G];
    constexpr unsigned sm  = CIRC.side[G];
    constexpr unsigned pml = pm & 63u;
    constexpr unsigned pmh = pm >> 6;
    constexpr unsigned sml = sm & 63u;
    constexpr unsigned smh = sm >> 6;
    constexpr bool flip = (__builtin_popcount(pml & sml) & 1) != 0;
    constexpr bool use_dpp = (pmh != 0u) && (dpp_cost(pmh) <= 2);

    const float u00r = m[0], u00i = m[1], u01r = m[2], u01i = m[3];
    const float u10r = m[4], u10i = m[5], u11r = m[6], u11i = m[7];

    const int sL = __popc(lane & (int)smh) & 1;
    const float p0r = sL ? u11r : u00r, p0i = sL ? u11i : u00i;
    const float q0r = sL ? u10r : u01r, q0i = sL ? u10i : u01i;
    const float p1r = sL ? u00r : u11r, p1i = sL ? u00i : u11i;
    const float q1r = sL ? u01r : u10r, q1i = sL ? u01i : u10i;
    const v2f P0R = {p0r, p0r}, P0N = {-p0i, p0i};
    const v2f Q0R = {q0r, q0r}, Q0N = {-q0i, q0i};
    const v2f P1R = {p1r, p1r}, P1N = {-p1i, p1i};
    const v2f Q1R = {q1r, q1r}, Q1N = {-q1i, q1i};

    if constexpr (pmh == 0u) {
        // purely in-thread pairs
        constexpr int msb = 1 << (31 - __builtin_clz(pml));
#pragma unroll
        for (int c = 0; c < 32; ++c) {
            const int j  = pidx(c, msb);
            const int j2 = j ^ (int)pml;
            const bool sj  = __builtin_parity(j & (int)sml);
            const bool sjB = flip ? !sj : sj;
            const v2f A = st[j], B = st[j2];
            st[j]  = cmadd(sj  ? P1R : P0R, sj  ? P1N : P0N, A,
                     cmul (sj  ? Q1R : Q0R, sj  ? Q1N : Q0N, B));
            st[j2] = cmadd(sjB ? P1R : P0R, sjB ? P1N : P0N, B,
                     cmul (sjB ? Q1R : Q0R, sjB ? Q1N : Q0N, A));
        }
    } else if constexpr (pml == 0u) {
        // pure cross-lane: partner is same j in lane ^ pmh
        if constexpr (use_dpp) {
#pragma unroll
            for (int j = 0; j < 64; ++j) {
                const v2f B = xpartner<pmh>(st[j], l16, l32);
                const bool sj = __builtin_parity(j & (int)sml);
                st[j] = cmadd(sj ? P1R : P0R, sj ? P1N : P0N, st[j],
                        cmul (sj ? Q1R : Q0R, sj ? Q1N : Q0N, B));
            }
        } else {
            // DS path, batched 8 elements (16 bpermutes) per chunk
#pragma unroll
            for (int j0 = 0; j0 < 64; j0 += 8) {
                v2f Bv[8];
#pragma unroll
                for (int k = 0; k < 8; ++k) {
                    Bv[k].x = __shfl_xor(st[j0 + k].x, (int)pmh, 64);
                    Bv[k].y = __shfl_xor(st[j0 + k].y, (int)pmh, 64);
                }
#pragma unroll
                for (int k = 0; k < 8; ++k) {
                    const int j = j0 + k;
                    const bool sj = __builtin_parity(j & (int)sml);
                    st[j] = cmadd(sj ? P1R : P0R, sj ? P1N : P0N, st[j],
                            cmul (sj ? Q1R : Q0R, sj ? Q1N : Q0N, Bv[k]));
                }
            }
        }
    } else {
        // mixed: partner is (lane ^ pmh, j ^ pml)
        constexpr int msb = 1 << (31 - __builtin_clz(pml));
        if constexpr (use_dpp) {
#pragma unroll
            for (int c = 0; c < 32; ++c) {
                const int j  = pidx(c, msb);
                const int j2 = j ^ (int)pml;
                const bool sj  = __builtin_parity(j & (int)sml);
                const bool sjB = flip ? !sj : sj;
                const v2f pa = xpartner<pmh>(st[j2], l16, l32);  // for output j
                const v2f pb = xpartner<pmh>(st[j],  l16, l32);  // for output j2
                const v2f A = st[j], B = st[j2];
                st[j]  = cmadd(sj  ? P1R : P0R, sj  ? P1N : P0N, A,
                         cmul (sj  ? Q1R : Q0R, sj  ? Q1N : Q0N, pa));
                st[j2] = cmadd(sjB ? P1R : P0R, sjB ? P1N : P0N, B,
                         cmul (sjB ? Q1R : Q0R, sjB ? Q1N : Q0N, pb));
            }
        } else {
            // DS path, batched 4 pairs (16 bpermutes) per chunk
#pragma unroll
            for (int c0 = 0; c0 < 32; c0 += 4) {
                v2f tA[4], tB[4];
#pragma unroll
                for (int k = 0; k < 4; ++k) {
                    const int j  = pidx(c0 + k, msb);
                    const int j2 = j ^ (int)pml;
                    tA[k].x = __shfl_xor(st[j2].x, (int)pmh, 64);
                    tA[k].y = __shfl_xor(st[j2].y, (int)pmh, 64);
                    tB[k].x = __shfl_xor(st[j].x,  (int)pmh, 64);
                    tB[k].y = __shfl_xor(st[j].y,  (int)pmh, 64);
                }
#pragma unroll
                for (int k = 0; k < 4; ++k) {
                    const int j  = pidx(c0 + k, msb);
                    const int j2 = j ^ (int)pml;
                    const bool sj  = __builtin_parity(j & (int)sml);
                    const bool sjB = flip ? !sj : sj;
                    const v2f A = st[j], B = st[j2];
                    st[j]  = cmadd(sj  ? P1R : P0R, sj  ? P1N : P0N, A,
                             cmul (sj  ? Q1R : Q0R, sj  ? Q1N : Q0N, tA[k]));
                    st[j2] = cmadd(sjB ? P1R : P0R, sjB ? P1N : P0N, B,
                             cmul (sjB ? Q1R : Q0R, sjB ? Q1N : Q0N, tB[k]));
                }
            }
        }
    }
}

template <int G>
__device__ __forceinline__ void apply_from(v2f (&st)[64], const float (*rotm)[8],
                                           int lane, bool l16, bool l32) {
    if constexpr (G < N_GATES) {
        apply_gate<G>(st, rotm[G], lane, l16, l32);
        apply_from<G + 1>(st, rotm, lane, l16, l32);
    }
}

__global__ __launch_bounds__(128, 3)
void qsim_kernel(const float* __restrict__ inputs,
                 const float* __restrict__ theta,
                 float* __restrict__ out, int B) {
    __shared__ float rotm[N_GATES][8];
    const int tid  = threadIdx.x;
    const int lane = tid & 63;
    const bool l16 = (lane & 16) != 0;
    const bool l32 = (lane & 32) != 0;
    int b = blockIdx.x * 2 + (tid >> 6);
    if (b >= B) b = B - 1;   // duplicate work, identical writes (B%2==0 normally)

    // ---- 48 shared Rot matrices (threads 0..47), PennyLane Rot(phi,th,om) ----
    if (tid < N_GATES) {
        const float* th = theta + tid * 3;   // tid = l*12 + w = gate index
        const float phi = th[0], tht = th[1], om = th[2];
        const float ct = __cosf(0.5f * tht), st = __sinf(0.5f * tht);
        const float a = 0.5f * (phi + om), d = 0.5f * (phi - om);
        const float ca = __cosf(a), sa = __sinf(a);
        const float cd = __cosf(d), sd = __sinf(d);
        rotm[tid][0] = ca * ct;  rotm[tid][1] = -sa * ct;   // u00 = e^{-ia} ct
        rotm[tid][2] = -cd * st; rotm[tid][3] = -sd * st;   // u01 = -e^{+id} st
        rotm[tid][4] = cd * st;  rotm[tid][5] = -sd * st;   // u10 = e^{-id} st
        rotm[tid][6] = ca * ct;  rotm[tid][7] = sa * ct;    // u11 = e^{+ia} ct
    }
    __syncthreads();

    // ---- init: RY-encoded product state (real) ----
    float cw[12], sw[12];
    const float* xin = inputs + b * 12;
#pragma unroll
    for (int w = 0; w < 12; ++w) {
        const float h = 0.5f * xin[w];
        cw[w] = __cosf(h);
        sw[w] = __sinf(h);
    }
    // lane bits: p bit (lb+6) <-> wire (5-lb)  =>  wire w (0..5) = lane bit (5-w)
    float prodL = 1.0f;
#pragma unroll
    for (int w = 0; w < 6; ++w)
        prodL *= ((lane >> (5 - w)) & 1) ? sw[w] : cw[w];

    float tmp[64];
    tmp[0] = prodL;
#pragma unroll
    for (int k = 0; k < 6; ++k) {            // local bit k <-> wire (11-k)
        const int n = 1 << k;
#pragma unroll
        for (int idx = 0; idx < n; ++idx) {
            const float v = tmp[idx];
            tmp[idx + n] = v * sw[11 - k];
            tmp[idx]     = v * cw[11 - k];
        }
    }
    v2f st[64];
#pragma unroll
    for (int j = 0; j < 64; ++j) st[j] = v2f{tmp[j], 0.0f};

    // ---- 4 layers x 12 Rot gates (CNOTs folded into masks) ----
    apply_from<0>(st, rotm, lane, l16, l32);

    // ---- measurement ----
    // w[m] = sum_j (-1)^{parity(j & m)} |st[j]|^2 via 6-stage local WHT
    float w[64];
#pragma unroll
    for (int j = 0; j < 64; ++j)
        w[j] = st[j].x * st[j].x + st[j].y * st[j].y;
#pragma unroll
    for (int t = 0; t < 6; ++t) {
        const int bit = 1 << t;
#pragma unroll
        for (int i = 0; i < 64; ++i) {
            if (!(i & bit)) {
                const float a = w[i], c = w[i | bit];
                w[i]       = a + c;
                w[i | bit] = a - c;
            }
        }
    }
    // <Z_q> = (-1)^{parity(lane & meas_hi)} * w[meas_lo], reduced over lanes
#pragma unroll
    for (int q = 0; q < 12; ++q) {
        float v = (__popc(lane & (int)(CIRC.meas[q] >> 6)) & 1)
                      ? -w[CIRC.meas[q] & 63u] : w[CIRC.meas[q] & 63u];
        v += __shfl_xor(v, 32, 64);
        v += __shfl_xor(v, 16, 64);
        v += __shfl_xor(v, 8, 64);
        v += __shfl_xor(v, 4, 64);
        v += __shfl_xor(v, 2, 64);
        v += __shfl_xor(v, 1, 64);
        if (lane == 0) out[b * 12 + q] = v;
    }
}

extern "C" void kernel_launch(void* const* d_in, const int* in_sizes, int n_in,
                              void* d_out, int out_size, void* d_ws, size_t ws_size,
                              hipStream_t stream) {
    const float* inputs = (const float*)d_in[0];
    const float* theta  = (const float*)d_in[1];
    float* out = (float*)d_out;
    const int B = in_sizes[0] / 12;
    const int blocks = (B + 1) / 2;
    qsim_kernel<<<blocks, 128, 0, stream>>>(inputs, theta, out, B);
}

// Round 11
// 328.350 us; speedup vs baseline: 1.1151x; 1.1151x over previous
//
#include <hip/hip_runtime.h>

// ---------------------------------------------------------------------------
// 12-qubit state-vector sim, one sample per 64-lane wave, 4 samples/block.
// Storage index p (12 bits): bits 0..5 = per-thread local index j,
// bits 6..11 = lane id. Logical k = M*p over GF(2); CNOTs folded into M at
// compile time; each Rot gate = pair-mask (col of M^-1) + side-mask (row M).
// Wire w <-> bit (11-w) of k (PennyLane big-endian).
//
// Packed layout: vector t = j>>1 holds halves h=0,1 (j bit0). rr[t]={re0,re1},
// ii[t]={im0,im1}. Complex update = pure packed FMAs (v_pk_fma_f32), side-bit
// variants baked into coefficient vectors at compile time.
//
// Round-11 change (vs failed R10): added the MISSING branch for gates with
// pmh==0 and ODD pml>1 (masks 3, 5, 0xF in layers 2/3/4): partner is
// (t^pmlv, h^1) -> needs .yx half-swap on the partner operand. R10 routed
// these through the even-pair branch (no swap) -> 3 wrong gates, absmax 0.08.
// All 48 masks re-audited against the branch taxonomy.
// ---------------------------------------------------------------------------

#define N_GATES 48

typedef float v2f __attribute__((ext_vector_type(2)));

#if __has_builtin(__builtin_amdgcn_permlane16_swap) && __has_builtin(__builtin_amdgcn_permlane32_swap)
#define HAS_PLSWAP 1
#else
#define HAS_PLSWAP 0
#endif

struct Circ {
    unsigned pair[N_GATES];
    unsigned side[N_GATES];
    unsigned meas[12];
};

constexpr Circ make_circ() {
    Circ c{};
    unsigned Mrow[12] = {}, Ucol[12] = {};   // M rows, M^-1 columns
    for (int i = 0; i < 12; ++i) { Mrow[i] = 1u << i; Ucol[i] = 1u << i; }
    int g = 0;
    for (int l = 0; l < 4; ++l) {
        for (int w = 0; w < 12; ++w) {
            int b = 11 - w;
            c.pair[g] = Ucol[b];
            c.side[g] = Mrow[b];
            ++g;
        }
        for (int i = 0; i < 11; ++i) {       // CNOT chain (i -> i+1)
            int cb = 11 - i, tb = 10 - i;
            Mrow[tb] ^= Mrow[cb];
            Ucol[cb] ^= Ucol[tb];
        }
        Mrow[11] ^= Mrow[0];                 // CNOT(11 -> 0)
        Ucol[0]  ^= Ucol[11];
    }
    for (int w = 0; w < 12; ++w) c.meas[w] = Mrow[11 - w];
    return c;
}

constexpr Circ CIRC = make_circ();

__device__ __forceinline__ constexpr int pidx(int c, int msb) {
    return ((c & ~(msb - 1)) << 1) | (c & (msb - 1));
}

constexpr int dpp_cost(unsigned pmh) {
    constexpr int low[16] = {0,1,1,1,2,2,2,1,2,3,3,3,2,2,2,1};
    int c = low[pmh & 15u];
    if (pmh & 16u) c += 2;
    if (pmh & 32u) c += 2;
    return c;
}

// ---- VALU-pipe lane-xor primitives --------------------------------------
__device__ __forceinline__ int dpp1(int w){ return __builtin_amdgcn_mov_dpp(w, 0xB1,  0xF, 0xF, true); }
__device__ __forceinline__ int dpp2(int w){ return __builtin_amdgcn_mov_dpp(w, 0x4E,  0xF, 0xF, true); }
__device__ __forceinline__ int dpp3(int w){ return __builtin_amdgcn_mov_dpp(w, 0x1B,  0xF, 0xF, true); }
__device__ __forceinline__ int dpp7(int w){ return __builtin_amdgcn_mov_dpp(w, 0x141, 0xF, 0xF, true); }
__device__ __forceinline__ int dppF(int w){ return __builtin_amdgcn_mov_dpp(w, 0x140, 0xF, 0xF, true); }

template <unsigned V>
__device__ __forceinline__ int dpp_low(int w) {
    if constexpr (V == 0)  return w;
    else if constexpr (V == 1)  return dpp1(w);
    else if constexpr (V == 2)  return dpp2(w);
    else if constexpr (V == 3)  return dpp3(w);
    else if constexpr (V == 7)  return dpp7(w);
    else if constexpr (V == 15) return dppF(w);
    else if constexpr (V == 4)  return dpp3(dpp7(w));
    else if constexpr (V == 5)  return dpp2(dpp7(w));
    else if constexpr (V == 6)  return dpp1(dpp7(w));
    else if constexpr (V == 8)  return dpp7(dppF(w));
    else if constexpr (V == 12) return dpp3(dppF(w));
    else if constexpr (V == 13) return dpp2(dppF(w));
    else if constexpr (V == 14) return dpp1(dppF(w));
    else if constexpr (V == 9)  return dpp1(dpp7(dppF(w)));
    else if constexpr (V == 10) return dpp2(dpp7(dppF(w)));
    else return dpp3(dpp7(dppF(w)));   // V == 11
}

template <unsigned PMH>
__device__ __forceinline__ unsigned xword(unsigned w, bool l16, bool l32) {
    unsigned t = (unsigned)dpp_low<PMH & 15u>((int)w);
#if HAS_PLSWAP
    if constexpr ((PMH & 16u) != 0) {
        auto r = __builtin_amdgcn_permlane16_swap(t, t, false, false);
        t = l16 ? r[0] : r[1];
    }
    if constexpr ((PMH & 32u) != 0) {
        auto r = __builtin_amdgcn_permlane32_swap(t, t, false, false);
        t = l32 ? r[0] : r[1];
    }
#else
    if constexpr ((PMH & 48u) != 0)
        t = (unsigned)__shfl_xor((int)t, (int)(PMH & 48u), 64);
#endif
    return t;
}

template <unsigned PMH>
__device__ __forceinline__ v2f xpartner(v2f v, bool l16, bool l32) {
    union { v2f f; unsigned u[2]; } a;
    a.f = v;
    a.u[0] = xword<PMH>(a.u[0], l16, l32);
    a.u[1] = xword<PMH>(a.u[1], l16, l32);
    return a.f;
}

// DS exchange with hoisted byte address (addr = (lane^pmh)<<2)
__device__ __forceinline__ v2f dsx(int addr, v2f v) {
    union { v2f f; int u[2]; } a;
    a.f = v;
    a.u[0] = __builtin_amdgcn_ds_bpermute(addr, a.u[0]);
    a.u[1] = __builtin_amdgcn_ds_bpermute(addr, a.u[1]);
    return a.f;
}

// out = c1*x1 + c2*x2 + c3*x3 + c4*x4 (packed, no swizzles)
__device__ __forceinline__ v2f fmad4(v2f c1, v2f x1, v2f c2, v2f x2,
                                     v2f c3, v2f x3, v2f c4, v2f x4) {
    return __builtin_elementwise_fma(c1, x1,
           __builtin_elementwise_fma(c2, x2,
           __builtin_elementwise_fma(c3, x3, c4 * x4)));
}

template <int G>
__device__ __forceinline__ void apply_gate(v2f (&rr)[32], v2f (&ii)[32],
                                           const float* __restrict__ m,
                                           int lane, bool l16, bool l32) {
    constexpr unsigned pm  = CIRC.pair[G];
    constexpr unsigned sm  = CIRC.side[G];
    constexpr unsigned pml = pm & 63u,  pmh = pm >> 6;
    constexpr unsigned sml = sm & 63u,  smh = sm >> 6;
    constexpr unsigned smlv = sml >> 1, pmlv = pml >> 1;
    constexpr bool smlodd = (sml & 1u) != 0;
    constexpr bool pmlodd = (pml & 1u) != 0;
    constexpr bool use_dpp = (pmh != 0u) && (dpp_cost(pmh) <= 1);

    const float u00r = m[0], u00i = m[1], u01r = m[2], u01i = m[3];
    const float u10r = m[4], u10i = m[5], u11r = m[6], u11i = m[7];
    const int sL = __popc(lane & (int)smh) & 1;
    // coef(s): own P(s)=s?u11:u00, partner Q(s)=s?u10:u01; a: s=sL, b: s=!sL
    const float par = sL ? u11r : u00r, pai = sL ? u11i : u00i;
    const float pbr = sL ? u00r : u11r, pbi = sL ? u00i : u11i;
    const float qar = sL ? u10r : u01r, qai = sL ? u10i : u01i;
    const float qbr = sL ? u01r : u10r, qbi = sL ? u01i : u10i;
    // element j=2t+h: s = sL ^ parity(t&smlv) ^ (h&smlodd).
    // variant c0 = parity(t&smlv): coef v2f halves = (s(h0), s(h1)).
    v2f PR0, PI0, PN0, QR0, QI0, QN0, PR1, PI1, PN1, QR1, QI1, QN1;
    if constexpr (!smlodd) {
        PR0 = v2f{par, par}; PI0 = v2f{pai, pai}; PN0 = v2f{-pai, -pai};
        QR0 = v2f{qar, qar}; QI0 = v2f{qai, qai}; QN0 = v2f{-qai, -qai};
        PR1 = v2f{pbr, pbr}; PI1 = v2f{pbi, pbi}; PN1 = v2f{-pbi, -pbi};
        QR1 = v2f{qbr, qbr}; QI1 = v2f{qbi, qbi}; QN1 = v2f{-qbi, -qbi};
    } else {
        PR0 = v2f{par, pbr}; PI0 = v2f{pai, pbi}; PN0 = v2f{-pai, -pbi};
        QR0 = v2f{qar, qbr}; QI0 = v2f{qai, qbi}; QN0 = v2f{-qai, -qbi};
        PR1 = v2f{pbr, par}; PI1 = v2f{pbi, pai}; PN1 = v2f{-pbi, -pai};
        QR1 = v2f{qbr, qar}; QI1 = v2f{qbi, qai}; QN1 = v2f{-qbi, -qai};
    }
#define CSEL(c, X) ((c) ? X##1 : X##0)
#define CRE(c, A, Ai, B, Bi) fmad4(CSEL(c,PR), A,  CSEL(c,PN), Ai, CSEL(c,QR), B,  CSEL(c,QN), Bi)
#define CIM(c, A, Ai, B, Bi) fmad4(CSEL(c,PR), Ai, CSEL(c,PI), A,  CSEL(c,QR), Bi, CSEL(c,QI), B)

    if constexpr (pmh == 0u && pml == 1u) {
        // partner inside the v2f: B = A.yx
#pragma unroll
        for (int t = 0; t < 32; ++t) {
            const int c0 = __builtin_parity(t & (int)smlv);
            const v2f A = rr[t], Ai = ii[t];
            const v2f B = A.yx, Bi = Ai.yx;
            rr[t] = CRE(c0, A, Ai, B, Bi);
            ii[t] = CIM(c0, A, Ai, B, Bi);
        }
    } else if constexpr (pmh == 0u && !pmlodd) {
        // in-thread vector pairs (t, t^pmlv), same half
        constexpr int msbv = 1 << (31 - __builtin_clz(pmlv));
#pragma unroll
        for (int c = 0; c < 16; ++c) {
            const int t = pidx(c, msbv), t2 = t ^ (int)pmlv;
            const int c0 = __builtin_parity(t  & (int)smlv);
            const int c1 = __builtin_parity(t2 & (int)smlv);
            const v2f A = rr[t], Ai = ii[t], B = rr[t2], Bi = ii[t2];
            rr[t]  = CRE(c0, A, Ai, B, Bi);
            ii[t]  = CIM(c0, A, Ai, B, Bi);
            rr[t2] = CRE(c1, B, Bi, A, Ai);
            ii[t2] = CIM(c1, B, Bi, A, Ai);
        }
    } else if constexpr (pmh == 0u) {
        // R11 FIX: in-thread pairs (t, t^pmlv) with HALF SWAP (pml odd > 1):
        // partner of (t,h) is (t^pmlv, h^1) -> .yx on partner operand.
        constexpr int msbv = 1 << (31 - __builtin_clz(pmlv));
#pragma unroll
        for (int c = 0; c < 16; ++c) {
            const int t = pidx(c, msbv), t2 = t ^ (int)pmlv;
            const int c0 = __builtin_parity(t  & (int)smlv);
            const int c1 = __builtin_parity(t2 & (int)smlv);
            const v2f A = rr[t], Ai = ii[t], B = rr[t2], Bi = ii[t2];
            const v2f BS = B.yx, BSi = Bi.yx, AS = A.yx, ASi = Ai.yx;
            rr[t]  = CRE(c0, A, Ai, BS, BSi);
            ii[t]  = CIM(c0, A, Ai, BS, BSi);
            rr[t2] = CRE(c1, B, Bi, AS, ASi);
            ii[t2] = CIM(c1, B, Bi, AS, ASi);
        }
    } else if constexpr (pml == 0u) {
        // pure cross-lane: partner = same vector, lane^pmh
        if constexpr (use_dpp) {
#pragma unroll
            for (int t = 0; t < 32; ++t) {
                const int c0 = __builtin_parity(t & (int)smlv);
                const v2f B  = xpartner<pmh>(rr[t], l16, l32);
                const v2f Bi = xpartner<pmh>(ii[t], l16, l32);
                const v2f A = rr[t], Ai = ii[t];
                rr[t] = CRE(c0, A, Ai, B, Bi);
                ii[t] = CIM(c0, A, Ai, B, Bi);
            }
        } else {
            const int bpa = ((lane ^ (int)pmh) << 2);
#pragma unroll
            for (int t0 = 0; t0 < 32; t0 += 4) {
                v2f B[4], Bi[4];
#pragma unroll
                for (int k = 0; k < 4; ++k) {
                    B[k]  = dsx(bpa, rr[t0 + k]);
                    Bi[k] = dsx(bpa, ii[t0 + k]);
                }
#pragma unroll
                for (int k = 0; k < 4; ++k) {
                    const int t = t0 + k;
                    const int c0 = __builtin_parity(t & (int)smlv);
                    const v2f A = rr[t], Ai = ii[t];
                    rr[t] = CRE(c0, A, Ai, B[k], Bi[k]);
                    ii[t] = CIM(c0, A, Ai, B[k], Bi[k]);
                }
            }
        }
    } else if constexpr (pmlodd && pmlv == 0u) {
        // partner = (lane^pmh, same t, h^1): exchange + half swap
        if constexpr (use_dpp) {
#pragma unroll
            for (int t = 0; t < 32; ++t) {
                const int c0 = __builtin_parity(t & (int)smlv);
                const v2f X  = xpartner<pmh>(rr[t], l16, l32);
                const v2f Xi = xpartner<pmh>(ii[t], l16, l32);
                const v2f A = rr[t], Ai = ii[t];
                const v2f B = X.yx, Bi = Xi.yx;
                rr[t] = CRE(c0, A, Ai, B, Bi);
                ii[t] = CIM(c0, A, Ai, B, Bi);
            }
        } else {
            const int bpa = ((lane ^ (int)pmh) << 2);
#pragma unroll
            for (int t0 = 0; t0 < 32; t0 += 4) {
                v2f X[4], Xi[4];
#pragma unroll
                for (int k = 0; k < 4; ++k) {
                    X[k]  = dsx(bpa, rr[t0 + k]);
                    Xi[k] = dsx(bpa, ii[t0 + k]);
                }
#pragma unroll
                for (int k = 0; k < 4; ++k) {
                    const int t = t0 + k;
                    const int c0 = __builtin_parity(t & (int)smlv);
                    const v2f A = rr[t], Ai = ii[t];
                    const v2f B = X[k].yx, Bi = Xi[k].yx;
                    rr[t] = CRE(c0, A, Ai, B, Bi);
                    ii[t] = CIM(c0, A, Ai, B, Bi);
                }
            }
        }
    } else if constexpr (pmlodd) {
        // pairs (t, t^pmlv) with lane exchange + half swap
        constexpr int msbv = 1 << (31 - __builtin_clz(pmlv));
        const int bpa = ((lane ^ (int)pmh) << 2);
#pragma unroll
        for (int c = 0; c < 16; ++c) {
            const int t = pidx(c, msbv), t2 = t ^ (int)pmlv;
            const int c0 = __builtin_parity(t  & (int)smlv);
            const int c1 = __builtin_parity(t2 & (int)smlv);
            v2f XA, XAi, XB, XBi;
            if constexpr (use_dpp) {
                XA  = xpartner<pmh>(rr[t2], l16, l32);
                XAi = xpartner<pmh>(ii[t2], l16, l32);
                XB  = xpartner<pmh>(rr[t],  l16, l32);
                XBi = xpartner<pmh>(ii[t],  l16, l32);
            } else {
                XA  = dsx(bpa, rr[t2]); XAi = dsx(bpa, ii[t2]);
                XB  = dsx(bpa, rr[t]);  XBi = dsx(bpa, ii[t]);
            }
            const v2f A = rr[t], Ai = ii[t], B = rr[t2], Bi = ii[t2];
            const v2f YA = XA.yx, YAi = XAi.yx, YB = XB.yx, YBi = XBi.yx;
            rr[t]  = CRE(c0, A, Ai, YA, YAi);
            ii[t]  = CIM(c0, A, Ai, YA, YAi);
            rr[t2] = CRE(c1, B, Bi, YB, YBi);
            ii[t2] = CIM(c1, B, Bi, YB, YBi);
        }
    } else {
        // mixed, pml even: pairs (t, t^pmlv) with lane exchange
        constexpr int msbv = 1 << (31 - __builtin_clz(pmlv));
        if constexpr (use_dpp) {
#pragma unroll
            for (int c = 0; c < 16; ++c) {
                const int t = pidx(c, msbv), t2 = t ^ (int)pmlv;
                const int c0 = __builtin_parity(t  & (int)smlv);
                const int c1 = __builtin_parity(t2 & (int)smlv);
                const v2f XA  = xpartner<pmh>(rr[t2], l16, l32);
                const v2f XAi = xpartner<pmh>(ii[t2], l16, l32);
                const v2f XB  = xpartner<pmh>(rr[t],  l16, l32);
                const v2f XBi = xpartner<pmh>(ii[t],  l16, l32);
                const v2f A = rr[t], Ai = ii[t], B = rr[t2], Bi = ii[t2];
                rr[t]  = CRE(c0, A, Ai, XA, XAi);
                ii[t]  = CIM(c0, A, Ai, XA, XAi);
                rr[t2] = CRE(c1, B, Bi, XB, XBi);
                ii[t2] = CIM(c1, B, Bi, XB, XBi);
            }
        } else {
            const int bpa = ((lane ^ (int)pmh) << 2);
#pragma unroll
            for (int cc = 0; cc < 16; cc += 2) {
                v2f XA[2], XAi[2], XB[2], XBi[2];
#pragma unroll
                for (int k = 0; k < 2; ++k) {
                    const int t = pidx(cc + k, msbv), t2 = t ^ (int)pmlv;
                    XA[k]  = dsx(bpa, rr[t2]); XAi[k] = dsx(bpa, ii[t2]);
                    XB[k]  = dsx(bpa, rr[t]);  XBi[k] = dsx(bpa, ii[t]);
                }
#pragma unroll
                for (int k = 0; k < 2; ++k) {
                    const int t = pidx(cc + k, msbv), t2 = t ^ (int)pmlv;
                    const int c0 = __builtin_parity(t  & (int)smlv);
                    const int c1 = __builtin_parity(t2 & (int)smlv);
                    const v2f A = rr[t], Ai = ii[t], B = rr[t2], Bi = ii[t2];
                    rr[t]  = CRE(c0, A, Ai, XA[k], XAi[k]);
                    ii[t]  = CIM(c0, A, Ai, XA[k], XAi[k]);
                    rr[t2] = CRE(c1, B, Bi, XB[k], XBi[k]);
                    ii[t2] = CIM(c1, B, Bi, XB[k], XBi[k]);
                }
            }
        }
    }
#undef CSEL
#undef CRE
#undef CIM
}

template <int G>
__device__ __forceinline__ void apply_from(v2f (&rr)[32], v2f (&ii)[32],
                                           const float (*rotm)[8],
                                           int lane, bool l16, bool l32) {
    if constexpr (G < N_GATES) {
        apply_gate<G>(rr, ii, rotm[G], lane, l16, l32);
        apply_from<G + 1>(rr, ii, rotm, lane, l16, l32);
    }
}

__global__ __launch_bounds__(256, 2)
void qsim_kernel(const float* __restrict__ inputs,
                 const float* __restrict__ theta,
                 float* __restrict__ out, int B) {
    __shared__ float rotm[N_GATES][8];
    const int tid  = threadIdx.x;
    const int lane = tid & 63;
    const bool l16 = (lane & 16) != 0;
    const bool l32 = (lane & 32) != 0;
    int b = blockIdx.x * 4 + (tid >> 6);
    if (b >= B) b = B - 1;

    // ---- 48 shared Rot matrices, PennyLane Rot(phi,th,om) ----
    if (tid < N_GATES) {
        const float* th = theta + tid * 3;
        const float phi = th[0], tht = th[1], om = th[2];
        const float ct = __cosf(0.5f * tht), st = __sinf(0.5f * tht);
        const float a = 0.5f * (phi + om), d = 0.5f * (phi - om);
        const float ca = __cosf(a), sa = __sinf(a);
        const float cd = __cosf(d), sd = __sinf(d);
        rotm[tid][0] = ca * ct;  rotm[tid][1] = -sa * ct;   // u00
        rotm[tid][2] = -cd * st; rotm[tid][3] = -sd * st;   // u01
        rotm[tid][4] = cd * st;  rotm[tid][5] = -sd * st;   // u10
        rotm[tid][6] = ca * ct;  rotm[tid][7] = sa * ct;    // u11
    }
    __syncthreads();

    // ---- init: RY-encoded product state (real) ----
    float cw[12], sw[12];
    const float* xin = inputs + b * 12;
#pragma unroll
    for (int w = 0; w < 12; ++w) {
        const float h = 0.5f * xin[w];
        cw[w] = __cosf(h);
        sw[w] = __sinf(h);
    }
    float prodL = 1.0f;
#pragma unroll
    for (int w = 0; w < 6; ++w)
        prodL *= ((lane >> (5 - w)) & 1) ? sw[w] : cw[w];

    // vector index t = j>>1 (j bits 1..5 <-> wires 10..6); h = j&1 <-> wire 11
    float tmp32[32];
    tmp32[0] = prodL;
#pragma unroll
    for (int k = 0; k < 5; ++k) {
        const int n = 1 << k;
#pragma unroll
        for (int idx = 0; idx < n; ++idx) {
            const float v = tmp32[idx];
            tmp32[idx + n] = v * sw[10 - k];
            tmp32[idx]     = v * cw[10 - k];
        }
    }
    v2f rr[32], ii[32];
#pragma unroll
    for (int t = 0; t < 32; ++t) {
        rr[t] = v2f{tmp32[t] * cw[11], tmp32[t] * sw[11]};
        ii[t] = v2f{0.0f, 0.0f};
    }

    // ---- 4 layers x 12 Rot gates (CNOTs folded into masks) ----
    apply_from<0>(rr, ii, rotm, lane, l16, l32);

    // ---- measurement: packed WHT over vector bits + per-q half-combine ----
    v2f pv[32];
#pragma unroll
    for (int t = 0; t < 32; ++t)
        pv[t] = __builtin_elementwise_fma(rr[t], rr[t], ii[t] * ii[t]);
#pragma unroll
    for (int s = 0; s < 5; ++s) {
        const int bit = 1 << s;
#pragma unroll
        for (int t = 0; t < 32; ++t) {
            if (!(t & bit)) {
                const v2f a = pv[t], d = pv[t | bit];
                pv[t]       = a + d;
                pv[t | bit] = a - d;
            }
        }
    }
#pragma unroll
    for (int q = 0; q < 12; ++q) {
        const unsigned mm = CIRC.meas[q];
        const int ml = (int)(mm & 63u), mv = ml >> 1;
        float v = (ml & 1) ? (pv[mv].x - pv[mv].y) : (pv[mv].x + pv[mv].y);
        if (__popc(lane & (int)(mm >> 6)) & 1) v = -v;
        v += __shfl_xor(v, 32, 64);
        v += __shfl_xor(v, 16, 64);
        v += __shfl_xor(v, 8, 64);
        v += __shfl_xor(v, 4, 64);
        v += __shfl_xor(v, 2, 64);
        v += __shfl_xor(v, 1, 64);
        if (lane == 0) out[b * 12 + q] = v;
    }
}

extern "C" void kernel_launch(void* const* d_in, const int* in_sizes, int n_in,
                              void* d_out, int out_size, void* d_ws, size_t ws_size,
                              hipStream_t stream) {
    const float* inputs = (const float*)d_in[0];
    const float* theta  = (const float*)d_in[1];
    float* out = (float*)d_out;
    const int B = in_sizes[0] / 12;
    const int blocks = (B + 3) / 4;
    qsim_kernel<<<blocks, 256, 0, stream>>>(inputs, theta, out, B);
}

// Round 12
// 308.182 us; speedup vs baseline: 1.1881x; 1.0654x over previous
//
#include <hip/hip_runtime.h>

// ---------------------------------------------------------------------------
// 12-qubit state-vector sim, one sample per 64-lane wave, 4 samples/block.
// Storage index p (12 bits): bits 0..5 = per-thread local index j,
// bits 6..11 = lane id. Logical k = M*p over GF(2); CNOTs folded into M at
// compile time; each Rot gate = pair-mask (col of M^-1) + side-mask (row M).
// Wire w <-> bit (11-w) of k (PennyLane big-endian).
//
// Packed layout (R11, kept): vector t = j>>1 holds halves h=0,1. rr[t]=
// {re0,re1}, ii[t]={im0,im1}. Complex update = pure packed FMAs, side-bit
// variants baked into coefficient vectors at compile time. Measured -16%
// VALU-busy vs R7's interleaved layout.
//
// Round-12 change (ONLY): DPP threshold restored to cost<=2 (R7 calibration).
// R11 lowered it to <=1 alongside the packed rewrite — confounded experiment:
// VALU work fell 16% but DS stalls grew to 40% (dur 312->328). R7's split
// (cost<=2 -> DPP: masks 1..8,12..16,32; cost>2 -> DS: 48,24,40,20,60,...)
// was the measured balance point. This recombines both wins cleanly.
// ---------------------------------------------------------------------------

#define N_GATES 48

typedef float v2f __attribute__((ext_vector_type(2)));

#if __has_builtin(__builtin_amdgcn_permlane16_swap) && __has_builtin(__builtin_amdgcn_permlane32_swap)
#define HAS_PLSWAP 1
#else
#define HAS_PLSWAP 0
#endif

struct Circ {
    unsigned pair[N_GATES];
    unsigned side[N_GATES];
    unsigned meas[12];
};

constexpr Circ make_circ() {
    Circ c{};
    unsigned Mrow[12] = {}, Ucol[12] = {};   // M rows, M^-1 columns
    for (int i = 0; i < 12; ++i) { Mrow[i] = 1u << i; Ucol[i] = 1u << i; }
    int g = 0;
    for (int l = 0; l < 4; ++l) {
        for (int w = 0; w < 12; ++w) {
            int b = 11 - w;
            c.pair[g] = Ucol[b];
            c.side[g] = Mrow[b];
            ++g;
        }
        for (int i = 0; i < 11; ++i) {       // CNOT chain (i -> i+1)
            int cb = 11 - i, tb = 10 - i;
            Mrow[tb] ^= Mrow[cb];
            Ucol[cb] ^= Ucol[tb];
        }
        Mrow[11] ^= Mrow[0];                 // CNOT(11 -> 0)
        Ucol[0]  ^= Ucol[11];
    }
    for (int w = 0; w < 12; ++w) c.meas[w] = Mrow[11 - w];
    return c;
}

constexpr Circ CIRC = make_circ();

__device__ __forceinline__ constexpr int pidx(int c, int msb) {
    return ((c & ~(msb - 1)) << 1) | (c & (msb - 1));
}

constexpr int dpp_cost(unsigned pmh) {
    constexpr int low[16] = {0,1,1,1,2,2,2,1,2,3,3,3,2,2,2,1};
    int c = low[pmh & 15u];
    if (pmh & 16u) c += 2;
    if (pmh & 32u) c += 2;
    return c;
}

// ---- VALU-pipe lane-xor primitives --------------------------------------
__device__ __forceinline__ int dpp1(int w){ return __builtin_amdgcn_mov_dpp(w, 0xB1,  0xF, 0xF, true); }
__device__ __forceinline__ int dpp2(int w){ return __builtin_amdgcn_mov_dpp(w, 0x4E,  0xF, 0xF, true); }
__device__ __forceinline__ int dpp3(int w){ return __builtin_amdgcn_mov_dpp(w, 0x1B,  0xF, 0xF, true); }
__device__ __forceinline__ int dpp7(int w){ return __builtin_amdgcn_mov_dpp(w, 0x141, 0xF, 0xF, true); }
__device__ __forceinline__ int dppF(int w){ return __builtin_amdgcn_mov_dpp(w, 0x140, 0xF, 0xF, true); }

template <unsigned V>
__device__ __forceinline__ int dpp_low(int w) {
    if constexpr (V == 0)  return w;
    else if constexpr (V == 1)  return dpp1(w);
    else if constexpr (V == 2)  return dpp2(w);
    else if constexpr (V == 3)  return dpp3(w);
    else if constexpr (V == 7)  return dpp7(w);
    else if constexpr (V == 15) return dppF(w);
    else if constexpr (V == 4)  return dpp3(dpp7(w));
    else if constexpr (V == 5)  return dpp2(dpp7(w));
    else if constexpr (V == 6)  return dpp1(dpp7(w));
    else if constexpr (V == 8)  return dpp7(dppF(w));
    else if constexpr (V == 12) return dpp3(dppF(w));
    else if constexpr (V == 13) return dpp2(dppF(w));
    else if constexpr (V == 14) return dpp1(dppF(w));
    else if constexpr (V == 9)  return dpp1(dpp7(dppF(w)));
    else if constexpr (V == 10) return dpp2(dpp7(dppF(w)));
    else return dpp3(dpp7(dppF(w)));   // V == 11
}

template <unsigned PMH>
__device__ __forceinline__ unsigned xword(unsigned w, bool l16, bool l32) {
    unsigned t = (unsigned)dpp_low<PMH & 15u>((int)w);
#if HAS_PLSWAP
    if constexpr ((PMH & 16u) != 0) {
        auto r = __builtin_amdgcn_permlane16_swap(t, t, false, false);
        t = l16 ? r[0] : r[1];
    }
    if constexpr ((PMH & 32u) != 0) {
        auto r = __builtin_amdgcn_permlane32_swap(t, t, false, false);
        t = l32 ? r[0] : r[1];
    }
#else
    if constexpr ((PMH & 48u) != 0)
        t = (unsigned)__shfl_xor((int)t, (int)(PMH & 48u), 64);
#endif
    return t;
}

template <unsigned PMH>
__device__ __forceinline__ v2f xpartner(v2f v, bool l16, bool l32) {
    union { v2f f; unsigned u[2]; } a;
    a.f = v;
    a.u[0] = xword<PMH>(a.u[0], l16, l32);
    a.u[1] = xword<PMH>(a.u[1], l16, l32);
    return a.f;
}

// DS exchange with hoisted byte address (addr = (lane^pmh)<<2)
__device__ __forceinline__ v2f dsx(int addr, v2f v) {
    union { v2f f; int u[2]; } a;
    a.f = v;
    a.u[0] = __builtin_amdgcn_ds_bpermute(addr, a.u[0]);
    a.u[1] = __builtin_amdgcn_ds_bpermute(addr, a.u[1]);
    return a.f;
}

// out = c1*x1 + c2*x2 + c3*x3 + c4*x4 (packed, no swizzles)
__device__ __forceinline__ v2f fmad4(v2f c1, v2f x1, v2f c2, v2f x2,
                                     v2f c3, v2f x3, v2f c4, v2f x4) {
    return __builtin_elementwise_fma(c1, x1,
           __builtin_elementwise_fma(c2, x2,
           __builtin_elementwise_fma(c3, x3, c4 * x4)));
}

template <int G>
__device__ __forceinline__ void apply_gate(v2f (&rr)[32], v2f (&ii)[32],
                                           const float* __restrict__ m,
                                           int lane, bool l16, bool l32) {
    constexpr unsigned pm  = CIRC.pair[G];
    constexpr unsigned sm  = CIRC.side[G];
    constexpr unsigned pml = pm & 63u,  pmh = pm >> 6;
    constexpr unsigned sml = sm & 63u,  smh = sm >> 6;
    constexpr unsigned smlv = sml >> 1, pmlv = pml >> 1;
    constexpr bool smlodd = (sml & 1u) != 0;
    constexpr bool pmlodd = (pml & 1u) != 0;
    constexpr bool use_dpp = (pmh != 0u) && (dpp_cost(pmh) <= 2);   // R7 calibration

    const float u00r = m[0], u00i = m[1], u01r = m[2], u01i = m[3];
    const float u10r = m[4], u10i = m[5], u11r = m[6], u11i = m[7];
    const int sL = __popc(lane & (int)smh) & 1;
    // coef(s): own P(s)=s?u11:u00, partner Q(s)=s?u10:u01; a: s=sL, b: s=!sL
    const float par = sL ? u11r : u00r, pai = sL ? u11i : u00i;
    const float pbr = sL ? u00r : u11r, pbi = sL ? u00i : u11i;
    const float qar = sL ? u10r : u01r, qai = sL ? u10i : u01i;
    const float qbr = sL ? u01r : u10r, qbi = sL ? u01i : u10i;
    // element j=2t+h: s = sL ^ parity(t&smlv) ^ (h&smlodd).
    // variant c0 = parity(t&smlv): coef v2f halves = (s(h0), s(h1)).
    v2f PR0, PI0, PN0, QR0, QI0, QN0, PR1, PI1, PN1, QR1, QI1, QN1;
    if constexpr (!smlodd) {
        PR0 = v2f{par, par}; PI0 = v2f{pai, pai}; PN0 = v2f{-pai, -pai};
        QR0 = v2f{qar, qar}; QI0 = v2f{qai, qai}; QN0 = v2f{-qai, -qai};
        PR1 = v2f{pbr, pbr}; PI1 = v2f{pbi, pbi}; PN1 = v2f{-pbi, -pbi};
        QR1 = v2f{qbr, qbr}; QI1 = v2f{qbi, qbi}; QN1 = v2f{-qbi, -qbi};
    } else {
        PR0 = v2f{par, pbr}; PI0 = v2f{pai, pbi}; PN0 = v2f{-pai, -pbi};
        QR0 = v2f{qar, qbr}; QI0 = v2f{qai, qbi}; QN0 = v2f{-qai, -qbi};
        PR1 = v2f{pbr, par}; PI1 = v2f{pbi, pai}; PN1 = v2f{-pbi, -pai};
        QR1 = v2f{qbr, qar}; QI1 = v2f{qbi, qai}; QN1 = v2f{-qbi, -qai};
    }
#define CSEL(c, X) ((c) ? X##1 : X##0)
#define CRE(c, A, Ai, B, Bi) fmad4(CSEL(c,PR), A,  CSEL(c,PN), Ai, CSEL(c,QR), B,  CSEL(c,QN), Bi)
#define CIM(c, A, Ai, B, Bi) fmad4(CSEL(c,PR), Ai, CSEL(c,PI), A,  CSEL(c,QR), Bi, CSEL(c,QI), B)

    if constexpr (pmh == 0u && pml == 1u) {
        // partner inside the v2f: B = A.yx
#pragma unroll
        for (int t = 0; t < 32; ++t) {
            const int c0 = __builtin_parity(t & (int)smlv);
            const v2f A = rr[t], Ai = ii[t];
            const v2f B = A.yx, Bi = Ai.yx;
            rr[t] = CRE(c0, A, Ai, B, Bi);
            ii[t] = CIM(c0, A, Ai, B, Bi);
        }
    } else if constexpr (pmh == 0u && !pmlodd) {
        // in-thread vector pairs (t, t^pmlv), same half
        constexpr int msbv = 1 << (31 - __builtin_clz(pmlv));
#pragma unroll
        for (int c = 0; c < 16; ++c) {
            const int t = pidx(c, msbv), t2 = t ^ (int)pmlv;
            const int c0 = __builtin_parity(t  & (int)smlv);
            const int c1 = __builtin_parity(t2 & (int)smlv);
            const v2f A = rr[t], Ai = ii[t], B = rr[t2], Bi = ii[t2];
            rr[t]  = CRE(c0, A, Ai, B, Bi);
            ii[t]  = CIM(c0, A, Ai, B, Bi);
            rr[t2] = CRE(c1, B, Bi, A, Ai);
            ii[t2] = CIM(c1, B, Bi, A, Ai);
        }
    } else if constexpr (pmh == 0u) {
        // in-thread pairs (t, t^pmlv) with HALF SWAP (pml odd > 1)
        constexpr int msbv = 1 << (31 - __builtin_clz(pmlv));
#pragma unroll
        for (int c = 0; c < 16; ++c) {
            const int t = pidx(c, msbv), t2 = t ^ (int)pmlv;
            const int c0 = __builtin_parity(t  & (int)smlv);
            const int c1 = __builtin_parity(t2 & (int)smlv);
            const v2f A = rr[t], Ai = ii[t], B = rr[t2], Bi = ii[t2];
            const v2f BS = B.yx, BSi = Bi.yx, AS = A.yx, ASi = Ai.yx;
            rr[t]  = CRE(c0, A, Ai, BS, BSi);
            ii[t]  = CIM(c0, A, Ai, BS, BSi);
            rr[t2] = CRE(c1, B, Bi, AS, ASi);
            ii[t2] = CIM(c1, B, Bi, AS, ASi);
        }
    } else if constexpr (pml == 0u) {
        // pure cross-lane: partner = same vector, lane^pmh
        if constexpr (use_dpp) {
#pragma unroll
            for (int t = 0; t < 32; ++t) {
                const int c0 = __builtin_parity(t & (int)smlv);
                const v2f B  = xpartner<pmh>(rr[t], l16, l32);
                const v2f Bi = xpartner<pmh>(ii[t], l16, l32);
                const v2f A = rr[t], Ai = ii[t];
                rr[t] = CRE(c0, A, Ai, B, Bi);
                ii[t] = CIM(c0, A, Ai, B, Bi);
            }
        } else {
            const int bpa = ((lane ^ (int)pmh) << 2);
#pragma unroll
            for (int t0 = 0; t0 < 32; t0 += 4) {
                v2f B[4], Bi[4];
#pragma unroll
                for (int k = 0; k < 4; ++k) {
                    B[k]  = dsx(bpa, rr[t0 + k]);
                    Bi[k] = dsx(bpa, ii[t0 + k]);
                }
#pragma unroll
                for (int k = 0; k < 4; ++k) {
                    const int t = t0 + k;
                    const int c0 = __builtin_parity(t & (int)smlv);
                    const v2f A = rr[t], Ai = ii[t];
                    rr[t] = CRE(c0, A, Ai, B[k], Bi[k]);
                    ii[t] = CIM(c0, A, Ai, B[k], Bi[k]);
                }
            }
        }
    } else if constexpr (pmlodd && pmlv == 0u) {
        // partner = (lane^pmh, same t, h^1): exchange + half swap
        if constexpr (use_dpp) {
#pragma unroll
            for (int t = 0; t < 32; ++t) {
                const int c0 = __builtin_parity(t & (int)smlv);
                const v2f X  = xpartner<pmh>(rr[t], l16, l32);
                const v2f Xi = xpartner<pmh>(ii[t], l16, l32);
                const v2f A = rr[t], Ai = ii[t];
                const v2f B = X.yx, Bi = Xi.yx;
                rr[t] = CRE(c0, A, Ai, B, Bi);
                ii[t] = CIM(c0, A, Ai, B, Bi);
            }
        } else {
            const int bpa = ((lane ^ (int)pmh) << 2);
#pragma unroll
            for (int t0 = 0; t0 < 32; t0 += 4) {
                v2f X[4], Xi[4];
#pragma unroll
                for (int k = 0; k < 4; ++k) {
                    X[k]  = dsx(bpa, rr[t0 + k]);
                    Xi[k] = dsx(bpa, ii[t0 + k]);
                }
#pragma unroll
                for (int k = 0; k < 4; ++k) {
                    const int t = t0 + k;
                    const int c0 = __builtin_parity(t & (int)smlv);
                    const v2f A = rr[t], Ai = ii[t];
                    const v2f B = X[k].yx, Bi = Xi[k].yx;
                    rr[t] = CRE(c0, A, Ai, B, Bi);
                    ii[t] = CIM(c0, A, Ai, B, Bi);
                }
            }
        }
    } else if constexpr (pmlodd) {
        // pairs (t, t^pmlv) with lane exchange + half swap
        constexpr int msbv = 1 << (31 - __builtin_clz(pmlv));
        const int bpa = ((lane ^ (int)pmh) << 2);
#pragma unroll
        for (int c = 0; c < 16; ++c) {
            const int t = pidx(c, msbv), t2 = t ^ (int)pmlv;
            const int c0 = __builtin_parity(t  & (int)smlv);
            const int c1 = __builtin_parity(t2 & (int)smlv);
            v2f XA, XAi, XB, XBi;
            if constexpr (use_dpp) {
                XA  = xpartner<pmh>(rr[t2], l16, l32);
                XAi = xpartner<pmh>(ii[t2], l16, l32);
                XB  = xpartner<pmh>(rr[t],  l16, l32);
                XBi = xpartner<pmh>(ii[t],  l16, l32);
            } else {
                XA  = dsx(bpa, rr[t2]); XAi = dsx(bpa, ii[t2]);
                XB  = dsx(bpa, rr[t]);  XBi = dsx(bpa, ii[t]);
            }
            const v2f A = rr[t], Ai = ii[t], B = rr[t2], Bi = ii[t2];
            const v2f YA = XA.yx, YAi = XAi.yx, YB = XB.yx, YBi = XBi.yx;
            rr[t]  = CRE(c0, A, Ai, YA, YAi);
            ii[t]  = CIM(c0, A, Ai, YA, YAi);
            rr[t2] = CRE(c1, B, Bi, YB, YBi);
            ii[t2] = CIM(c1, B, Bi, YB, YBi);
        }
    } else {
        // mixed, pml even: pairs (t, t^pmlv) with lane exchange
        constexpr int msbv = 1 << (31 - __builtin_clz(pmlv));
        if constexpr (use_dpp) {
#pragma unroll
            for (int c = 0; c < 16; ++c) {
                const int t = pidx(c, msbv), t2 = t ^ (int)pmlv;
                const int c0 = __builtin_parity(t  & (int)smlv);
                const int c1 = __builtin_parity(t2 & (int)smlv);
                const v2f XA  = xpartner<pmh>(rr[t2], l16, l32);
                const v2f XAi = xpartner<pmh>(ii[t2], l16, l32);
                const v2f XB  = xpartner<pmh>(rr[t],  l16, l32);
                const v2f XBi = xpartner<pmh>(ii[t],  l16, l32);
                const v2f A = rr[t], Ai = ii[t], B = rr[t2], Bi = ii[t2];
                rr[t]  = CRE(c0, A, Ai, XA, XAi);
                ii[t]  = CIM(c0, A, Ai, XA, XAi);
                rr[t2] = CRE(c1, B, Bi, XB, XBi);
                ii[t2] = CIM(c1, B, Bi, XB, XBi);
            }
        } else {
            const int bpa = ((lane ^ (int)pmh) << 2);
#pragma unroll
            for (int cc = 0; cc < 16; cc += 2) {
                v2f XA[2], XAi[2], XB[2], XBi[2];
#pragma unroll
                for (int k = 0; k < 2; ++k) {
                    const int t = pidx(cc + k, msbv), t2 = t ^ (int)pmlv;
                    XA[k]  = dsx(bpa, rr[t2]); XAi[k] = dsx(bpa, ii[t2]);
                    XB[k]  = dsx(bpa, rr[t]);  XBi[k] = dsx(bpa, ii[t]);
                }
#pragma unroll
                for (int k = 0; k < 2; ++k) {
                    const int t = pidx(cc + k, msbv), t2 = t ^ (int)pmlv;
                    const int c0 = __builtin_parity(t  & (int)smlv);
                    const int c1 = __builtin_parity(t2 & (int)smlv);
                    const v2f A = rr[t], Ai = ii[t], B = rr[t2], Bi = ii[t2];
                    rr[t]  = CRE(c0, A, Ai, XA[k], XAi[k]);
                    ii[t]  = CIM(c0, A, Ai, XA[k], XAi[k]);
                    rr[t2] = CRE(c1, B, Bi, XB[k], XBi[k]);
                    ii[t2] = CIM(c1, B, Bi, XB[k], XBi[k]);
                }
            }
        }
    }
#undef CSEL
#undef CRE
#undef CIM
}

template <int G>
__device__ __forceinline__ void apply_from(v2f (&rr)[32], v2f (&ii)[32],
                                           const float (*rotm)[8],
                                           int lane, bool l16, bool l32) {
    if constexpr (G < N_GATES) {
        apply_gate<G>(rr, ii, rotm[G], lane, l16, l32);
        apply_from<G + 1>(rr, ii, rotm, lane, l16, l32);
    }
}

__global__ __launch_bounds__(256, 2)
void qsim_kernel(const float* __restrict__ inputs,
                 const float* __restrict__ theta,
                 float* __restrict__ out, int B) {
    __shared__ float rotm[N_GATES][8];
    const int tid  = threadIdx.x;
    const int lane = tid & 63;
    const bool l16 = (lane & 16) != 0;
    const bool l32 = (lane & 32) != 0;
    int b = blockIdx.x * 4 + (tid >> 6);
    if (b >= B) b = B - 1;

    // ---- 48 shared Rot matrices, PennyLane Rot(phi,th,om) ----
    if (tid < N_GATES) {
        const float* th = theta + tid * 3;
        const float phi = th[0], tht = th[1], om = th[2];
        const float ct = __cosf(0.5f * tht), st = __sinf(0.5f * tht);
        const float a = 0.5f * (phi + om), d = 0.5f * (phi - om);
        const float ca = __cosf(a), sa = __sinf(a);
        const float cd = __cosf(d), sd = __sinf(d);
        rotm[tid][0] = ca * ct;  rotm[tid][1] = -sa * ct;   // u00
        rotm[tid][2] = -cd * st; rotm[tid][3] = -sd * st;   // u01
        rotm[tid][4] = cd * st;  rotm[tid][5] = -sd * st;   // u10
        rotm[tid][6] = ca * ct;  rotm[tid][7] = sa * ct;    // u11
    }
    __syncthreads();

    // ---- init: RY-encoded product state (real) ----
    float cw[12], sw[12];
    const float* xin = inputs + b * 12;
#pragma unroll
    for (int w = 0; w < 12; ++w) {
        const float h = 0.5f * xin[w];
        cw[w] = __cosf(h);
        sw[w] = __sinf(h);
    }
    float prodL = 1.0f;
#pragma unroll
    for (int w = 0; w < 6; ++w)
        prodL *= ((lane >> (5 - w)) & 1) ? sw[w] : cw[w];

    // vector index t = j>>1 (j bits 1..5 <-> wires 10..6); h = j&1 <-> wire 11
    float tmp32[32];
    tmp32[0] = prodL;
#pragma unroll
    for (int k = 0; k < 5; ++k) {
        const int n = 1 << k;
#pragma unroll
        for (int idx = 0; idx < n; ++idx) {
            const float v = tmp32[idx];
            tmp32[idx + n] = v * sw[10 - k];
            tmp32[idx]     = v * cw[10 - k];
        }
    }
    v2f rr[32], ii[32];
#pragma unroll
    for (int t = 0; t < 32; ++t) {
        rr[t] = v2f{tmp32[t] * cw[11], tmp32[t] * sw[11]};
        ii[t] = v2f{0.0f, 0.0f};
    }

    // ---- 4 layers x 12 Rot gates (CNOTs folded into masks) ----
    apply_from<0>(rr, ii, rotm, lane, l16, l32);

    // ---- measurement: packed WHT over vector bits + per-q half-combine ----
    v2f pv[32];
#pragma unroll
    for (int t = 0; t < 32; ++t)
        pv[t] = __builtin_elementwise_fma(rr[t], rr[t], ii[t] * ii[t]);
#pragma unroll
    for (int s = 0; s < 5; ++s) {
        const int bit = 1 << s;
#pragma unroll
        for (int t = 0; t < 32; ++t) {
            if (!(t & bit)) {
                const v2f a = pv[t], d = pv[t | bit];
                pv[t]       = a + d;
                pv[t | bit] = a - d;
            }
        }
    }
#pragma unroll
    for (int q = 0; q < 12; ++q) {
        const unsigned mm = CIRC.meas[q];
        const int ml = (int)(mm & 63u), mv = ml >> 1;
        float v = (ml & 1) ? (pv[mv].x - pv[mv].y) : (pv[mv].x + pv[mv].y);
        if (__popc(lane & (int)(mm >> 6)) & 1) v = -v;
        v += __shfl_xor(v, 32, 64);
        v += __shfl_xor(v, 16, 64);
        v += __shfl_xor(v, 8, 64);
        v += __shfl_xor(v, 4, 64);
        v += __shfl_xor(v, 2, 64);
        v += __shfl_xor(v, 1, 64);
        if (lane == 0) out[b * 12 + q] = v;
    }
}

extern "C" void kernel_launch(void* const* d_in, const int* in_sizes, int n_in,
                              void* d_out, int out_size, void* d_ws, size_t ws_size,
                              hipStream_t stream) {
    const float* inputs = (const float*)d_in[0];
    const float* theta  = (const float*)d_in[1];
    float* out = (float*)d_out;
    const int B = in_sizes[0] / 12;
    const int blocks = (B + 3) / 4;
    qsim_kernel<<<blocks, 256, 0, stream>>>(inputs, theta, out, B);
}